// Round 3
// baseline (332.348 us; speedup 1.0000x reference)
//
#include <hip/hip_runtime.h>
#include <math.h>

#define NROWS 65536
#define DIM   512
#define NCLS  64
#define CCAP  1280   // per-class bucket capacity (mean 1024, sd ~32 -> 8 sigma)

typedef __attribute__((ext_vector_type(4))) float f32x4;
typedef __attribute__((ext_vector_type(8))) short s16x8;

// ws layout (4-byte words):
//   [0..32768)      protoSum[64][512] f32   (zeroed)
//   [32768..32832)  cursors[64] i32         (zeroed; == counts after scatter)
//   32832 lossAcc   32833 accAcc   32834 doneCnt   (zeroed)
//   [32836..32900)  p2[64] f32
//   [32912..114832) perm[64*1280] i32
//   [114944..131328) pBf bf16[64*512] in MFMA B-fragment order
#define WS_PROTOSUM 0
#define WS_CURSORS  32768
#define WS_LOSS     32832
#define WS_ACC      32833
#define WS_DONE     32834
#define WS_P2       32836
#define WS_PERM     32912
#define WS_PBF      114944           // byte 459776, 16B aligned
#define MEMSET_WORDS 32835

static __device__ __forceinline__ unsigned short f2bf(float f) {
    unsigned int u = __float_as_uint(f);
    u += 0x7FFF + ((u >> 16) & 1);   // RNE
    return (unsigned short)(u >> 16);
}
static __device__ __forceinline__ float bf2f(unsigned short h) {
    return __uint_as_float(((unsigned int)h) << 16);
}

// async global->LDS DMA, 16B per lane; LDS dest = wave-uniform base + lane*16.
// Casts match the builtin's exact signature (void AS1* / void AS3*).
static __device__ __forceinline__ void gll16(const float* g, float* l) {
    __builtin_amdgcn_global_load_lds(
        (const __attribute__((address_space(1))) void*)g,
        (__attribute__((address_space(3))) void*)l,
        16, 0, 0);
}

// ---------------- scatter rows into fixed-stride class buckets ------------
__global__ __launch_bounds__(256) void k_scatter(const int* __restrict__ labels,
                                                 int* __restrict__ cursors,
                                                 int* __restrict__ perm) {
    __shared__ int lh[NCLS], lb[NCLS];
    int t = threadIdx.x;
    if (t < NCLS) lh[t] = 0;
    __syncthreads();
    int i = blockIdx.x * 256 + t;
    int lab = labels[i];
    int rank = atomicAdd(&lh[lab], 1);
    __syncthreads();
    if (t < NCLS) lb[t] = atomicAdd(&cursors[t], lh[t]);
    __syncthreads();
    int pos = lb[lab] + rank;
    if (pos < CCAP) perm[lab * CCAP + pos] = i;
}

// ---------------- per-class partial sums, float4 register accumulation ----
// grid = 64 classes x 4 dim-chunks x 8 row-splits = 2048 blocks
__global__ __launch_bounds__(256) void k_psum(const float* __restrict__ emb,
                                              const int* __restrict__ cursors,
                                              const int* __restrict__ perm,
                                              float* __restrict__ protoSum) {
    __shared__ int permS[CCAP];
    __shared__ float4 red[256];
    int t   = threadIdx.x;
    int c   = blockIdx.x >> 5;
    int sub = blockIdx.x & 31;
    int dc  = sub & 3;        // dim chunk (128 dims)
    int rs  = sub >> 2;       // row split 0..7
    int tl  = t & 31;
    int g   = t >> 5;         // 0..7

    int cnt = cursors[c];
    int n = (cnt < CCAP) ? cnt : CCAP;
    for (int i = t; i < n; i += 256) permS[i] = perm[c * CCAP + i];
    __syncthreads();

    const float4* eb = (const float4*)emb + dc * 32 + tl;
    float4 acc = make_float4(0.f, 0.f, 0.f, 0.f);
#pragma unroll 4
    for (int i = rs * 8 + g; i < n; i += 64) {
        int r = permS[i];                       // LDS broadcast
        float4 v = eb[(size_t)r * 128];         // 512B contiguous per row-grp
        acc.x += v.x; acc.y += v.y; acc.z += v.z; acc.w += v.w;
    }
    red[t] = acc;
    __syncthreads();
    if (t < 32) {
        float4 s = red[t];
#pragma unroll
        for (int gg = 1; gg < 8; ++gg) {
            float4 v = red[gg * 32 + t];
            s.x += v.x; s.y += v.y; s.z += v.z; s.w += v.w;
        }
        float* dst = &protoSum[(size_t)c * DIM + dc * 128 + t * 4];
        atomicAdd(dst + 0, s.x);
        atomicAdd(dst + 1, s.y);
        atomicAdd(dst + 2, s.z);
        atomicAdd(dst + 3, s.w);
    }
}

// ---- finalize prototypes: mean -> bf16 B in MFMA fragment order, p2 ------
// pBf layout: shorts idx = (((kc*4+quad)*4+nt)*16 + l15)*8 + j
__global__ __launch_bounds__(512) void k_protofin(const float* __restrict__ protoSum,
                                                  const int* __restrict__ cursors,
                                                  unsigned short* __restrict__ pBf,
                                                  float* __restrict__ p2) {
    int c = blockIdx.x, d = threadIdx.x;
    float mean = protoSum[(size_t)c * DIM + d] / (float)cursors[c];
    unsigned short mb = f2bf(mean);
    int kc = d >> 5, quad = (d >> 3) & 3, j = d & 7;
    int nt = c >> 4, l15 = c & 15;
    pBf[(size_t)(((kc * 4 + quad) * 4 + nt) * 16 + l15) * 8 + j] = mb;
    float mf = bf2f(mb);
    float sq = mf * mf;
#pragma unroll
    for (int o = 32; o > 0; o >>= 1) sq += __shfl_down(sq, o, 64);
    __shared__ float red[8];
    if ((d & 63) == 0) red[d >> 6] = sq;
    __syncthreads();
    if (d == 0) {
        float ss = 0.f;
#pragma unroll
        for (int w = 0; w < 8; ++w) ss += red[w];
        p2[c] = ss;
    }
}

// ---------------- main: MFMA + per-wave LDS ring via global_load_lds ------
// grid = 1024 x 256; wave wv owns rows wv*16..+15 exclusively -> NO barriers.
// A streamed through a 4-slot/wave LDS ring (2 KB/slot = 16 rows x 128B)
// with counted vmcnt so 2-3 chunks stay in flight per wave at all times
// (outstanding bytes/CU ~80 KB >> latency-BW product ~10 KB).
// LDS rows are XOR-swizzled (16B seg s' = s ^ (row&7)) on BOTH the DMA's
// per-lane GLOBAL source address and the ds_read offset; LDS dest stays
// linear (global_load_lds writes base + lane*16) per rule #21.
#define LROWS 64
#define LGRID (NROWS / LROWS)
__global__ __launch_bounds__(256, 4) void k_logits(const float* __restrict__ emb,
                                                const int* __restrict__ labels,
                                                const unsigned short* __restrict__ pBf,
                                                const float* __restrict__ p2,
                                                float* __restrict__ lossAcc,
                                                float* __restrict__ accAcc,
                                                unsigned int* __restrict__ doneCnt,
                                                float* __restrict__ out) {
    __shared__ __align__(16) float Ach[4][4][16][32]; // [wave][ring][row][f] 32 KB
    __shared__ float e2s[LROWS];
    __shared__ float rb[8];

    int t    = threadIdx.x;
    int lane = t & 63;
    int wv   = t >> 6;
    int quad = lane >> 4;
    int l15  = lane & 15;
    int rbase = blockIdx.x * LROWS;

    f32x4 acc[4];
#pragma unroll
    for (int nt = 0; nt < 4; ++nt) acc[nt] = (f32x4){0.f, 0.f, 0.f, 0.f};
    float e2a = 0.f;

    // DMA source: lane covers row (lane>>3) of the 8-row half-chunk, and the
    // pre-swizzled 16B segment (lane&7)^row of the 128B row chunk.
    int drow = lane >> 3;
    int dcol = 4 * ((lane & 7) ^ drow);
    const float* gDMA = emb + (size_t)(rbase + wv * 16 + drow) * DIM + dcol;
    float* ldsW = &Ach[wv][0][0][0];   // ring slot s at +s*512 floats; half i at +i*256

    // swizzled ds_read offsets (floats): row l15, quad's two 16B segments
    int rofs0 = l15 * 32 + (((quad * 2)     ^ (l15 & 7)) << 2);
    int rofs1 = l15 * 32 + (((quad * 2 + 1) ^ (l15 & 7)) << 2);

    const s16x8* bp = (const s16x8*)pBf + quad * 64 + l15;

    // prologue, FIFO order: A0(2) B0(4) A1(2) A2(2)  -> 10 outstanding
    gll16(gDMA,        ldsW);
    gll16(gDMA + 4096, ldsW + 256);
    asm volatile("" ::: "memory");
    s16x8 bcur[4];
#pragma unroll
    for (int nt = 0; nt < 4; ++nt) bcur[nt] = bp[nt * 16];
    asm volatile("" ::: "memory");
    gll16(gDMA + 32,        ldsW + 512);
    gll16(gDMA + 32 + 4096, ldsW + 512 + 256);
    gll16(gDMA + 64,        ldsW + 1024);
    gll16(gDMA + 64 + 4096, ldsW + 1024 + 256);

#pragma unroll
    for (int kc = 0; kc < 16; ++kc) {
        // B(kc+1) prefetch (plain loads; fenced so FIFO order = B then A-DMA)
        s16x8 bnxt[4];
        if (kc + 1 < 16) {
#pragma unroll
            for (int nt = 0; nt < 4; ++nt) bnxt[nt] = bp[(kc + 1) * 256 + nt * 16];
        }
        asm volatile("" ::: "memory");
        // A(kc+3) DMA into ring slot (kc+3)&3 (never the slot read this iter)
        if (kc + 3 < 16) {
            int s = (kc + 3) & 3;
            gll16(gDMA + (kc + 3) * 32,        ldsW + s * 512);
            gll16(gDMA + (kc + 3) * 32 + 4096, ldsW + s * 512 + 256);
        }
        // counted waits (FIFO-exact): retire A(kc),B(kc); keep 2-3 chunks in flight
        if      (kc == 0)  asm volatile("s_waitcnt vmcnt(10)" ::: "memory");
        else if (kc <= 12) asm volatile("s_waitcnt vmcnt(8)"  ::: "memory");
        else if (kc == 13) asm volatile("s_waitcnt vmcnt(6)"  ::: "memory");
        else if (kc == 14) asm volatile("s_waitcnt vmcnt(4)"  ::: "memory");
        else               asm volatile("s_waitcnt vmcnt(0)"  ::: "memory");

        const float* slot = ldsW + (kc & 3) * 512;
        float4 a0 = *(const float4*)(slot + rofs0);
        float4 a1 = *(const float4*)(slot + rofs1);
        e2a += a0.x * a0.x + a0.y * a0.y + a0.z * a0.z + a0.w * a0.w
             + a1.x * a1.x + a1.y * a1.y + a1.z * a1.z + a1.w * a1.w;
        s16x8 a;
        a[0] = f2bf(a0.x); a[1] = f2bf(a0.y); a[2] = f2bf(a0.z); a[3] = f2bf(a0.w);
        a[4] = f2bf(a1.x); a[5] = f2bf(a1.y); a[6] = f2bf(a1.z); a[7] = f2bf(a1.w);
#pragma unroll
        for (int nt = 0; nt < 4; ++nt)
            acc[nt] = __builtin_amdgcn_mfma_f32_16x16x32_bf16(a, bcur[nt], acc[nt], 0, 0, 0);
        if (kc + 1 < 16) {
#pragma unroll
            for (int nt = 0; nt < 4; ++nt) bcur[nt] = bnxt[nt];
        }
    }

    // lane (quad,l15) holds e2 partial of row l15 over k = quad*8+j (mod 32)
    e2a += __shfl_xor(e2a, 16, 64);
    e2a += __shfl_xor(e2a, 32, 64);
    if (quad == 0) e2s[wv * 16 + l15] = e2a;
    __syncthreads();

    // epilogue: C/D layout col = nt*16 + l15, row = quad*4 + reg
    float nlls = 0.f, corr = 0.f;
#pragma unroll
    for (int reg = 0; reg < 4; ++reg) {
        int rloc = wv * 16 + quad * 4 + reg;
        float e2v = e2s[rloc];
        float lg[4];
#pragma unroll
        for (int nt = 0; nt < 4; ++nt) {
            float d2 = e2v + p2[nt * 16 + l15] - 2.f * acc[nt][reg];
            d2 = fmaxf(d2, 1e-12f);
            lg[nt] = -sqrtf(d2);
        }
        float mv = lg[0]; int mc = l15;
#pragma unroll
        for (int nt = 1; nt < 4; ++nt) {
            int cix = nt * 16 + l15;
            if (lg[nt] > mv) { mv = lg[nt]; mc = cix; }
        }
#pragma unroll
        for (int o = 1; o < 16; o <<= 1) {
            float mo = __shfl_xor(mv, o, 64);
            int   co = __shfl_xor(mc, o, 64);
            if (mo > mv || (mo == mv && co < mc)) { mv = mo; mc = co; }
        }
        int lab = labels[rbase + rloc];
        float se = 0.f, ll = 0.f;
#pragma unroll
        for (int nt = 0; nt < 4; ++nt) se += __expf(lg[nt] - mv);
        if ((lab & 15) == l15) ll = lg[lab >> 4];
#pragma unroll
        for (int o = 1; o < 16; o <<= 1) {
            se += __shfl_xor(se, o, 64);
            ll += __shfl_xor(ll, o, 64);
        }
        if (l15 == 0) {
            nlls += __logf(se) + mv - ll;
            corr += (mc == lab) ? 1.f : 0.f;
        }
    }
#pragma unroll
    for (int o = 1; o < 64; o <<= 1) {
        nlls += __shfl_xor(nlls, o, 64);
        corr += __shfl_xor(corr, o, 64);
    }
    if (lane == 0) { rb[wv] = nlls; rb[4 + wv] = corr; }
    __syncthreads();
    if (t == 0) {
        atomicAdd(lossAcc, rb[0] + rb[1] + rb[2] + rb[3]);
        atomicAdd(accAcc, rb[4] + rb[5] + rb[6] + rb[7]);
        __threadfence();
        unsigned int tk = atomicAdd(doneCnt, 1u);
        if (tk == LGRID - 1) {   // last block: all atomics visible
            float ls  = atomicAdd(lossAcc, 0.f);   // device-scope read
            float as_ = atomicAdd(accAcc, 0.f);
            out[0] = ls * (1.f / NROWS);
            out[1] = as_ * (1.f / NROWS);
        }
    }
}

extern "C" void kernel_launch(void* const* d_in, const int* in_sizes, int n_in,
                              void* d_out, int out_size, void* d_ws, size_t ws_size,
                              hipStream_t stream) {
    const float* emb    = (const float*)d_in[0];
    const int*   labels = (const int*)d_in[1];
    float* out = (float*)d_out;

    float* wsf = (float*)d_ws;
    int*   wsi = (int*)d_ws;
    float*          protoSum = wsf + WS_PROTOSUM;
    int*            cursors  = wsi + WS_CURSORS;
    float*          lossAcc  = wsf + WS_LOSS;
    float*          accAcc   = wsf + WS_ACC;
    unsigned int*   doneCnt  = (unsigned int*)(wsi + WS_DONE);
    float*          p2       = wsf + WS_P2;
    int*            perm     = wsi + WS_PERM;
    unsigned short* pBf      = (unsigned short*)(wsf + WS_PBF);

    hipMemsetAsync(d_ws, 0, MEMSET_WORDS * sizeof(int), stream);

    k_scatter<<<NROWS / 256, 256, 0, stream>>>(labels, cursors, perm);
    k_psum<<<NCLS * 32, 256, 0, stream>>>(emb, cursors, perm, protoSum);
    k_protofin<<<NCLS, 512, 0, stream>>>(protoSum, cursors, pBf, p2);
    k_logits<<<LGRID, 256, 0, stream>>>(emb, labels, pBf, p2,
                                        lossAcc, accAcc, doneCnt, out);
}

// Round 4
// 322.962 us; speedup vs baseline: 1.0291x; 1.0291x over previous
//
#include <hip/hip_runtime.h>
#include <math.h>

#define NROWS 65536
#define DIM   512
#define NCLS  64
#define CCAP  1280   // per-class bucket capacity (mean 1024, sd ~32 -> 8 sigma)

typedef __attribute__((ext_vector_type(4))) float f32x4;
typedef __attribute__((ext_vector_type(8))) short s16x8;

// ws layout (4-byte words):
//   [0..32768)      protoSum[64][512] f32   (zeroed)
//   [32768..32832)  cursors[64] i32         (zeroed; == counts after scatter)
//   32832 lossAcc   32833 accAcc   32834 doneCnt   (zeroed)
//   [32836..32900)  p2[64] f32
//   [32912..114832) perm[64*1280] i32
//   [114944..131328) pBf bf16[64*512] in MFMA B-fragment order
#define WS_PROTOSUM 0
#define WS_CURSORS  32768
#define WS_LOSS     32832
#define WS_ACC      32833
#define WS_DONE     32834
#define WS_P2       32836
#define WS_PERM     32912
#define WS_PBF      114944           // byte 459776, 16B aligned
#define MEMSET_WORDS 32835

static __device__ __forceinline__ unsigned short f2bf(float f) {
    unsigned int u = __float_as_uint(f);
    u += 0x7FFF + ((u >> 16) & 1);   // RNE
    return (unsigned short)(u >> 16);
}
static __device__ __forceinline__ float bf2f(unsigned short h) {
    return __uint_as_float(((unsigned int)h) << 16);
}

// ---------------- scatter rows into fixed-stride class buckets ------------
__global__ __launch_bounds__(256) void k_scatter(const int* __restrict__ labels,
                                                 int* __restrict__ cursors,
                                                 int* __restrict__ perm) {
    __shared__ int lh[NCLS], lb[NCLS];
    int t = threadIdx.x;
    if (t < NCLS) lh[t] = 0;
    __syncthreads();
    int i = blockIdx.x * 256 + t;
    int lab = labels[i];
    int rank = atomicAdd(&lh[lab], 1);
    __syncthreads();
    if (t < NCLS) lb[t] = atomicAdd(&cursors[t], lh[t]);
    __syncthreads();
    int pos = lb[lab] + rank;
    if (pos < CCAP) perm[lab * CCAP + pos] = i;
}

// ---------------- per-class partial sums, float4 register accumulation ----
// grid = 64 classes x 4 dim-chunks x 8 row-splits = 2048 blocks
__global__ __launch_bounds__(256) void k_psum(const float* __restrict__ emb,
                                              const int* __restrict__ cursors,
                                              const int* __restrict__ perm,
                                              float* __restrict__ protoSum) {
    __shared__ int permS[CCAP];
    __shared__ float4 red[256];
    int t   = threadIdx.x;
    int c   = blockIdx.x >> 5;
    int sub = blockIdx.x & 31;
    int dc  = sub & 3;        // dim chunk (128 dims)
    int rs  = sub >> 2;       // row split 0..7
    int tl  = t & 31;
    int g   = t >> 5;         // 0..7

    int cnt = cursors[c];
    int n = (cnt < CCAP) ? cnt : CCAP;
    for (int i = t; i < n; i += 256) permS[i] = perm[c * CCAP + i];
    __syncthreads();

    const float4* eb = (const float4*)emb + dc * 32 + tl;
    float4 acc = make_float4(0.f, 0.f, 0.f, 0.f);
#pragma unroll 4
    for (int i = rs * 8 + g; i < n; i += 64) {
        int r = permS[i];                       // LDS broadcast
        float4 v = eb[(size_t)r * 128];         // 512B contiguous per row-grp
        acc.x += v.x; acc.y += v.y; acc.z += v.z; acc.w += v.w;
    }
    red[t] = acc;
    __syncthreads();
    if (t < 32) {
        float4 s = red[t];
#pragma unroll
        for (int gg = 1; gg < 8; ++gg) {
            float4 v = red[gg * 32 + t];
            s.x += v.x; s.y += v.y; s.z += v.z; s.w += v.w;
        }
        float* dst = &protoSum[(size_t)c * DIM + dc * 128 + t * 4];
        atomicAdd(dst + 0, s.x);
        atomicAdd(dst + 1, s.y);
        atomicAdd(dst + 2, s.z);
        atomicAdd(dst + 3, s.w);
    }
}

// ---- finalize prototypes: mean -> bf16 B in MFMA fragment order, p2 ------
// pBf layout: shorts idx = (((kc*4+quad)*4+nt)*16 + l15)*8 + j
__global__ __launch_bounds__(512) void k_protofin(const float* __restrict__ protoSum,
                                                  const int* __restrict__ cursors,
                                                  unsigned short* __restrict__ pBf,
                                                  float* __restrict__ p2) {
    int c = blockIdx.x, d = threadIdx.x;
    float mean = protoSum[(size_t)c * DIM + d] / (float)cursors[c];
    unsigned short mb = f2bf(mean);
    int kc = d >> 5, quad = (d >> 3) & 3, j = d & 7;
    int nt = c >> 4, l15 = c & 15;
    pBf[(size_t)(((kc * 4 + quad) * 4 + nt) * 16 + l15) * 8 + j] = mb;
    float mf = bf2f(mb);
    float sq = mf * mf;
#pragma unroll
    for (int o = 32; o > 0; o >>= 1) sq += __shfl_down(sq, o, 64);
    __shared__ float red[8];
    if ((d & 63) == 0) red[d >> 6] = sq;
    __syncthreads();
    if (d == 0) {
        float ss = 0.f;
#pragma unroll
        for (int w = 0; w < 8; ++w) ss += red[w];
        p2[c] = ss;
    }
}

// ---------------- main: MFMA, K-split x2, all-A-upfront register prefetch -
// grid = 2048 x 256; block covers 32 rows. Waves: (rwv = wv&1) picks the
// 16-row group, (kh = wv>>1) picks the K-half (kc 0-7 or 8-15). Each wave
// issues ALL 16 of its A-loads (16 KB) up front -> whole K-half in flight
// before compute; 8 gated steps per wave (was 16); 8192 total waves (2x).
// kh=1 partial acc/e2 combine into kh=0 via stride-17 LDS (conflict-free),
// one __syncthreads total. Accumulation order within each K-half unchanged.
#define LROWS 32
#define LGRID (NROWS / LROWS)
__global__ __launch_bounds__(256) void k_logits(const float* __restrict__ emb,
                                                const int* __restrict__ labels,
                                                const unsigned short* __restrict__ pBf,
                                                const float* __restrict__ p2,
                                                float* __restrict__ lossAcc,
                                                float* __restrict__ accAcc,
                                                unsigned int* __restrict__ doneCnt,
                                                float* __restrict__ out) {
    __shared__ float accS[2][64][17];   // [rwv][lane][16 acc vals], stride 17
    __shared__ float e2sA[32], e2sB[32];
    __shared__ float rb[8];

    int t    = threadIdx.x;
    int lane = t & 63;
    int wv   = t >> 6;
    int rwv  = wv & 1;       // which 16-row group of the block
    int kh   = wv >> 1;      // which K-half (0: kc 0-7, 1: kc 8-15)
    int quad = lane >> 4;
    int l15  = lane & 15;
    int rbase = blockIdx.x * LROWS + rwv * 16;   // this wave's 16-row base

    f32x4 acc[4];
#pragma unroll
    for (int nt = 0; nt < 4; ++nt) acc[nt] = (f32x4){0.f, 0.f, 0.f, 0.f};
    float e2a = 0.f;

    const float4* rp = (const float4*)(emb + (size_t)(rbase + l15) * DIM) + quad * 2;
    const s16x8*  bp = (const s16x8*)pBf + quad * 64 + l15;
    int kb = kh * 8;

    // B prologue first (oldest in FIFO), then the full A burst for this K-half
    s16x8 bcur[4];
#pragma unroll
    for (int nt = 0; nt < 4; ++nt) bcur[nt] = bp[(size_t)kb * 256 + nt * 16];

    float4 ga[16];                       // 64 VGPRs, all statically indexed
#pragma unroll
    for (int i = 0; i < 8; ++i) {
        ga[2 * i]     = rp[(kb + i) * 8];
        ga[2 * i + 1] = rp[(kb + i) * 8 + 1];
    }

#pragma unroll
    for (int i = 0; i < 8; ++i) {
        int kc = kb + i;
        s16x8 bnxt[4];
        if (i < 7) {
#pragma unroll
            for (int nt = 0; nt < 4; ++nt) bnxt[nt] = bp[(size_t)(kc + 1) * 256 + nt * 16];
        }
        float4 g0 = ga[2 * i];
        float4 g1 = ga[2 * i + 1];
        e2a += g0.x * g0.x + g0.y * g0.y + g0.z * g0.z + g0.w * g0.w
             + g1.x * g1.x + g1.y * g1.y + g1.z * g1.z + g1.w * g1.w;
        s16x8 a;
        a[0] = f2bf(g0.x); a[1] = f2bf(g0.y); a[2] = f2bf(g0.z); a[3] = f2bf(g0.w);
        a[4] = f2bf(g1.x); a[5] = f2bf(g1.y); a[6] = f2bf(g1.z); a[7] = f2bf(g1.w);
#pragma unroll
        for (int nt = 0; nt < 4; ++nt)
            acc[nt] = __builtin_amdgcn_mfma_f32_16x16x32_bf16(a, bcur[nt], acc[nt], 0, 0, 0);
        if (i < 7) {
#pragma unroll
            for (int nt = 0; nt < 4; ++nt) bcur[nt] = bnxt[nt];
        }
    }

    // e2 partial for this K-half: sum quads -> row-sum over 256 dims
    e2a += __shfl_xor(e2a, 16, 64);
    e2a += __shfl_xor(e2a, 32, 64);
    if (quad == 0) {
        if (kh == 0) e2sA[rwv * 16 + l15] = e2a;
        else         e2sB[rwv * 16 + l15] = e2a;
    }
    // kh=1 exports its partial accumulators (stride-17: conflict-free)
    if (kh == 1) {
#pragma unroll
        for (int nt = 0; nt < 4; ++nt)
#pragma unroll
            for (int r = 0; r < 4; ++r)
                accS[rwv][lane][nt * 4 + r] = acc[nt][r];
    }
    __syncthreads();

    // epilogue on kh=0 waves only: combine halves, then softmax/nll/argmax
    float nlls = 0.f, corr = 0.f;
    if (kh == 0) {
#pragma unroll
        for (int nt = 0; nt < 4; ++nt)
#pragma unroll
            for (int r = 0; r < 4; ++r)
                acc[nt][r] += accS[rwv][lane][nt * 4 + r];

#pragma unroll
        for (int reg = 0; reg < 4; ++reg) {
            int rowblk = rwv * 16 + quad * 4 + reg;       // block-local row
            float e2v = e2sA[rowblk] + e2sB[rowblk];
            float lg[4];
#pragma unroll
            for (int nt = 0; nt < 4; ++nt) {
                float d2 = e2v + p2[nt * 16 + l15] - 2.f * acc[nt][reg];
                d2 = fmaxf(d2, 1e-12f);
                lg[nt] = -sqrtf(d2);
            }
            float mv = lg[0]; int mc = l15;
#pragma unroll
            for (int nt = 1; nt < 4; ++nt) {
                int cix = nt * 16 + l15;
                if (lg[nt] > mv) { mv = lg[nt]; mc = cix; }
            }
#pragma unroll
            for (int o = 1; o < 16; o <<= 1) {
                float mo = __shfl_xor(mv, o, 64);
                int   co = __shfl_xor(mc, o, 64);
                if (mo > mv || (mo == mv && co < mc)) { mv = mo; mc = co; }
            }
            int lab = labels[blockIdx.x * LROWS + rowblk];
            float se = 0.f, ll = 0.f;
#pragma unroll
            for (int nt = 0; nt < 4; ++nt) se += __expf(lg[nt] - mv);
            if ((lab & 15) == l15) ll = lg[lab >> 4];
#pragma unroll
            for (int o = 1; o < 16; o <<= 1) {
                se += __shfl_xor(se, o, 64);
                ll += __shfl_xor(ll, o, 64);
            }
            if (l15 == 0) {
                nlls += __logf(se) + mv - ll;
                corr += (mc == lab) ? 1.f : 0.f;
            }
        }
    }
#pragma unroll
    for (int o = 1; o < 64; o <<= 1) {
        nlls += __shfl_xor(nlls, o, 64);
        corr += __shfl_xor(corr, o, 64);
    }
    if (lane == 0) { rb[wv] = nlls; rb[4 + wv] = corr; }
    __syncthreads();
    if (t == 0) {
        atomicAdd(lossAcc, rb[0] + rb[1] + rb[2] + rb[3]);
        atomicAdd(accAcc, rb[4] + rb[5] + rb[6] + rb[7]);
        __threadfence();
        unsigned int tk = atomicAdd(doneCnt, 1u);
        if (tk == LGRID - 1) {   // last block: all atomics visible
            float ls  = atomicAdd(lossAcc, 0.f);   // device-scope read
            float as_ = atomicAdd(accAcc, 0.f);
            out[0] = ls * (1.f / NROWS);
            out[1] = as_ * (1.f / NROWS);
        }
    }
}

extern "C" void kernel_launch(void* const* d_in, const int* in_sizes, int n_in,
                              void* d_out, int out_size, void* d_ws, size_t ws_size,
                              hipStream_t stream) {
    const float* emb    = (const float*)d_in[0];
    const int*   labels = (const int*)d_in[1];
    float* out = (float*)d_out;

    float* wsf = (float*)d_ws;
    int*   wsi = (int*)d_ws;
    float*          protoSum = wsf + WS_PROTOSUM;
    int*            cursors  = wsi + WS_CURSORS;
    float*          lossAcc  = wsf + WS_LOSS;
    float*          accAcc   = wsf + WS_ACC;
    unsigned int*   doneCnt  = (unsigned int*)(wsi + WS_DONE);
    float*          p2       = wsf + WS_P2;
    int*            perm     = wsi + WS_PERM;
    unsigned short* pBf      = (unsigned short*)(wsf + WS_PBF);

    hipMemsetAsync(d_ws, 0, MEMSET_WORDS * sizeof(int), stream);

    k_scatter<<<NROWS / 256, 256, 0, stream>>>(labels, cursors, perm);
    k_psum<<<NCLS * 32, 256, 0, stream>>>(emb, cursors, perm, protoSum);
    k_protofin<<<NCLS, 512, 0, stream>>>(protoSum, cursors, pBf, p2);
    k_logits<<<LGRID, 256, 0, stream>>>(emb, labels, pBf, p2,
                                        lossAcc, accAcc, doneCnt, out);
}

// Round 6
// 303.841 us; speedup vs baseline: 1.0938x; 1.0629x over previous
//
#include <hip/hip_runtime.h>
#include <math.h>

#define NROWS 65536
#define DIM   512
#define NCLS  64
#define CCAP  1280   // per-class bucket capacity (mean 1024, sd ~32 -> 8 sigma)

typedef __attribute__((ext_vector_type(4))) float f32x4;
typedef __attribute__((ext_vector_type(8))) short s16x8;

// ws layout (4-byte words):
//   [0..32768)      protoSum[64][512] f32   (zeroed)
//   [32768..32832)  cursors[64] i32         (zeroed; == counts after scatter)
//   32832 lossAcc   32833 accAcc   32834 doneCnt   (zeroed)
//   [32836..32900)  p2[64] f32
//   [32912..114832) perm[64*1280] i32
//   [114944..131328) pBf bf16[64*512] in MFMA B-fragment order
#define WS_PROTOSUM 0
#define WS_CURSORS  32768
#define WS_LOSS     32832
#define WS_ACC      32833
#define WS_DONE     32834
#define WS_P2       32836
#define WS_PERM     32912
#define WS_PBF      114944           // byte 459776, 16B aligned
#define MEMSET_WORDS 32835

static __device__ __forceinline__ unsigned short f2bf(float f) {
    unsigned int u = __float_as_uint(f);
    u += 0x7FFF + ((u >> 16) & 1);   // RNE
    return (unsigned short)(u >> 16);
}
static __device__ __forceinline__ float bf2f(unsigned short h) {
    return __uint_as_float(((unsigned int)h) << 16);
}

// ---------------- scatter rows into fixed-stride class buckets ------------
__global__ __launch_bounds__(256) void k_scatter(const int* __restrict__ labels,
                                                 int* __restrict__ cursors,
                                                 int* __restrict__ perm) {
    __shared__ int lh[NCLS], lb[NCLS];
    int t = threadIdx.x;
    if (t < NCLS) lh[t] = 0;
    __syncthreads();
    int i = blockIdx.x * 256 + t;
    int lab = labels[i];
    int rank = atomicAdd(&lh[lab], 1);
    __syncthreads();
    if (t < NCLS) lb[t] = atomicAdd(&cursors[t], lh[t]);
    __syncthreads();
    int pos = lb[lab] + rank;
    if (pos < CCAP) perm[lab * CCAP + pos] = i;
}

// ---------------- per-class partial sums, float4 register accumulation ----
// grid = 64 classes x 4 dim-chunks x 8 row-splits = 2048 blocks
__global__ __launch_bounds__(256) void k_psum(const float* __restrict__ emb,
                                              const int* __restrict__ cursors,
                                              const int* __restrict__ perm,
                                              float* __restrict__ protoSum) {
    __shared__ int permS[CCAP];
    __shared__ float4 red[256];
    int t   = threadIdx.x;
    int c   = blockIdx.x >> 5;
    int sub = blockIdx.x & 31;
    int dc  = sub & 3;        // dim chunk (128 dims)
    int rs  = sub >> 2;       // row split 0..7
    int tl  = t & 31;
    int g   = t >> 5;         // 0..7

    int cnt = cursors[c];
    int n = (cnt < CCAP) ? cnt : CCAP;
    for (int i = t; i < n; i += 256) permS[i] = perm[c * CCAP + i];
    __syncthreads();

    const float4* eb = (const float4*)emb + dc * 32 + tl;
    float4 acc = make_float4(0.f, 0.f, 0.f, 0.f);
#pragma unroll 4
    for (int i = rs * 8 + g; i < n; i += 64) {
        int r = permS[i];                       // LDS broadcast
        float4 v = eb[(size_t)r * 128];         // 512B contiguous per row-grp
        acc.x += v.x; acc.y += v.y; acc.z += v.z; acc.w += v.w;
    }
    red[t] = acc;
    __syncthreads();
    if (t < 32) {
        float4 s = red[t];
#pragma unroll
        for (int gg = 1; gg < 8; ++gg) {
            float4 v = red[gg * 32 + t];
            s.x += v.x; s.y += v.y; s.z += v.z; s.w += v.w;
        }
        float* dst = &protoSum[(size_t)c * DIM + dc * 128 + t * 4];
        atomicAdd(dst + 0, s.x);
        atomicAdd(dst + 1, s.y);
        atomicAdd(dst + 2, s.z);
        atomicAdd(dst + 3, s.w);
    }
}

// ---- finalize prototypes: mean -> bf16 B in MFMA fragment order, p2 ------
// pBf layout: shorts idx = (((kc*4+quad)*4+nt)*16 + l15)*8 + j
__global__ __launch_bounds__(512) void k_protofin(const float* __restrict__ protoSum,
                                                  const int* __restrict__ cursors,
                                                  unsigned short* __restrict__ pBf,
                                                  float* __restrict__ p2) {
    int c = blockIdx.x, d = threadIdx.x;
    float mean = protoSum[(size_t)c * DIM + d] / (float)cursors[c];
    unsigned short mb = f2bf(mean);
    int kc = d >> 5, quad = (d >> 3) & 3, j = d & 7;
    int nt = c >> 4, l15 = c & 15;
    pBf[(size_t)(((kc * 4 + quad) * 4 + nt) * 16 + l15) * 8 + j] = mb;
    float mf = bf2f(mb);
    float sq = mf * mf;
#pragma unroll
    for (int o = 32; o > 0; o >>= 1) sq += __shfl_down(sq, o, 64);
    __shared__ float red[8];
    if ((d & 63) == 0) red[d >> 6] = sq;
    __syncthreads();
    if (d == 0) {
        float ss = 0.f;
#pragma unroll
        for (int w = 0; w < 8; ++w) ss += red[w];
        p2[c] = ss;
    }
}

// ---------------- main: MFMA, two-phase (stream-then-reload) --------------
// grid = 1024 x 256; wave wv owns rows wv*16..+15 exclusively -> NO barriers.
// Phase 1: pure streaming e2 reduction over the wave's 16 KB A-set in 4
// chunks of 8 named float4 loads (the load-cluster pattern LLVM pipelines
// deep) -> saturates HBM AND warms L2/L3 with this wave's data.
// Phase 2: re-walk the same addresses in REVERSE kc order (hottest-first,
// L2/L3 hits, so depth-1 scheduling is harmless), convert to bf16, MFMA.
// An empty asm memory barrier (no operands, no waitcnt text) separates the
// phases so phase-2 reloads cannot be CSE'd against phase-1 values.
#define LROWS 64
#define LGRID (NROWS / LROWS)
__global__ __launch_bounds__(256, 4) void k_logits(const float* __restrict__ emb,
                                                const int* __restrict__ labels,
                                                const unsigned short* __restrict__ pBf,
                                                const float* __restrict__ p2,
                                                float* __restrict__ lossAcc,
                                                float* __restrict__ accAcc,
                                                unsigned int* __restrict__ doneCnt,
                                                float* __restrict__ out) {
    __shared__ float e2s[LROWS];
    __shared__ float rb[8];

    int t    = threadIdx.x;
    int lane = t & 63;
    int wv   = t >> 6;
    int quad = lane >> 4;
    int l15  = lane & 15;
    int rbase = blockIdx.x * LROWS;
    int row   = wv * 16 + l15;        // block-local row this lane feeds MFMA

    f32x4 acc[4];
#pragma unroll
    for (int nt = 0; nt < 4; ++nt) acc[nt] = (f32x4){0.f, 0.f, 0.f, 0.f};

    const float4* rp = (const float4*)(emb + (size_t)(rbase + row) * DIM) + quad * 2;
    const s16x8*  bp = (const s16x8*)pBf + quad * 64 + l15;

    // ---- phase 1: streaming e2 over all 16 kc (kc order preserved) ----
    float e2a = 0.f;
#pragma unroll
    for (int ch = 0; ch < 4; ++ch) {
        int k0 = ch * 4;
        float4 c0 = rp[(k0 + 0) * 8], c1 = rp[(k0 + 0) * 8 + 1];
        float4 c2 = rp[(k0 + 1) * 8], c3 = rp[(k0 + 1) * 8 + 1];
        float4 c4 = rp[(k0 + 2) * 8], c5 = rp[(k0 + 2) * 8 + 1];
        float4 c6 = rp[(k0 + 3) * 8], c7 = rp[(k0 + 3) * 8 + 1];
        e2a += c0.x * c0.x + c0.y * c0.y + c0.z * c0.z + c0.w * c0.w
             + c1.x * c1.x + c1.y * c1.y + c1.z * c1.z + c1.w * c1.w;
        e2a += c2.x * c2.x + c2.y * c2.y + c2.z * c2.z + c2.w * c2.w
             + c3.x * c3.x + c3.y * c3.y + c3.z * c3.z + c3.w * c3.w;
        e2a += c4.x * c4.x + c4.y * c4.y + c4.z * c4.z + c4.w * c4.w
             + c5.x * c5.x + c5.y * c5.y + c5.z * c5.z + c5.w * c5.w;
        e2a += c6.x * c6.x + c6.y * c6.y + c6.z * c6.z + c6.w * c6.w
             + c7.x * c7.x + c7.y * c7.y + c7.z * c7.z + c7.w * c7.w;
    }

    // phase separator: compiler-level memory barrier, zero instructions
    asm volatile("" ::: "memory");

    // ---- phase 2: reload (cache-hot, LIFO order) -> bf16 -> MFMA ----
#pragma unroll 4
    for (int i = 0; i < 16; ++i) {
        int kc = 15 - i;
        float4 g0 = rp[kc * 8];
        float4 g1 = rp[kc * 8 + 1];
        s16x8 a;
        a[0] = f2bf(g0.x); a[1] = f2bf(g0.y); a[2] = f2bf(g0.z); a[3] = f2bf(g0.w);
        a[4] = f2bf(g1.x); a[5] = f2bf(g1.y); a[6] = f2bf(g1.z); a[7] = f2bf(g1.w);
#pragma unroll
        for (int nt = 0; nt < 4; ++nt) {
            s16x8 b = bp[(size_t)kc * 256 + nt * 16];
            acc[nt] = __builtin_amdgcn_mfma_f32_16x16x32_bf16(a, b, acc[nt], 0, 0, 0);
        }
    }

    // lane (quad,l15) holds full ||row l15||^2 partial over k = quad*8+j (mod 32)
    e2a += __shfl_xor(e2a, 16, 64);
    e2a += __shfl_xor(e2a, 32, 64);
    if (quad == 0) e2s[row] = e2a;
    __syncthreads();

    // epilogue: C/D layout col = nt*16 + l15, row = quad*4 + reg
    float nlls = 0.f, corr = 0.f;
#pragma unroll
    for (int reg = 0; reg < 4; ++reg) {
        int rloc = wv * 16 + quad * 4 + reg;
        float e2v = e2s[rloc];
        float lg[4];
#pragma unroll
        for (int nt = 0; nt < 4; ++nt) {
            float d2 = e2v + p2[nt * 16 + l15] - 2.f * acc[nt][reg];
            d2 = fmaxf(d2, 1e-12f);
            lg[nt] = -sqrtf(d2);
        }
        float mv = lg[0]; int mc = l15;
#pragma unroll
        for (int nt = 1; nt < 4; ++nt) {
            int cix = nt * 16 + l15;
            if (lg[nt] > mv) { mv = lg[nt]; mc = cix; }
        }
#pragma unroll
        for (int o = 1; o < 16; o <<= 1) {
            float mo = __shfl_xor(mv, o, 64);
            int   co = __shfl_xor(mc, o, 64);
            if (mo > mv || (mo == mv && co < mc)) { mv = mo; mc = co; }
        }
        int lab = labels[rbase + rloc];
        float se = 0.f, ll = 0.f;
#pragma unroll
        for (int nt = 0; nt < 4; ++nt) se += __expf(lg[nt] - mv);
        if ((lab & 15) == l15) ll = lg[lab >> 4];
#pragma unroll
        for (int o = 1; o < 16; o <<= 1) {
            se += __shfl_xor(se, o, 64);
            ll += __shfl_xor(ll, o, 64);
        }
        if (l15 == 0) {
            nlls += __logf(se) + mv - ll;
            corr += (mc == lab) ? 1.f : 0.f;
        }
    }
#pragma unroll
    for (int o = 1; o < 64; o <<= 1) {
        nlls += __shfl_xor(nlls, o, 64);
        corr += __shfl_xor(corr, o, 64);
    }
    if (lane == 0) { rb[wv] = nlls; rb[4 + wv] = corr; }
    __syncthreads();
    if (t == 0) {
        atomicAdd(lossAcc, rb[0] + rb[1] + rb[2] + rb[3]);
        atomicAdd(accAcc, rb[4] + rb[5] + rb[6] + rb[7]);
        __threadfence();
        unsigned int tk = atomicAdd(doneCnt, 1u);
        if (tk == LGRID - 1) {   // last block: all atomics visible
            float ls  = atomicAdd(lossAcc, 0.f);   // device-scope read
            float as_ = atomicAdd(accAcc, 0.f);
            out[0] = ls * (1.f / NROWS);
            out[1] = as_ * (1.f / NROWS);
        }
    }
}

extern "C" void kernel_launch(void* const* d_in, const int* in_sizes, int n_in,
                              void* d_out, int out_size, void* d_ws, size_t ws_size,
                              hipStream_t stream) {
    const float* emb    = (const float*)d_in[0];
    const int*   labels = (const int*)d_in[1];
    float* out = (float*)d_out;

    float* wsf = (float*)d_ws;
    int*   wsi = (int*)d_ws;
    float*          protoSum = wsf + WS_PROTOSUM;
    int*            cursors  = wsi + WS_CURSORS;
    float*          lossAcc  = wsf + WS_LOSS;
    float*          accAcc   = wsf + WS_ACC;
    unsigned int*   doneCnt  = (unsigned int*)(wsi + WS_DONE);
    float*          p2       = wsf + WS_P2;
    int*            perm     = wsi + WS_PERM;
    unsigned short* pBf      = (unsigned short*)(wsf + WS_PBF);

    hipMemsetAsync(d_ws, 0, MEMSET_WORDS * sizeof(int), stream);

    k_scatter<<<NROWS / 256, 256, 0, stream>>>(labels, cursors, perm);
    k_psum<<<NCLS * 32, 256, 0, stream>>>(emb, cursors, perm, protoSum);
    k_protofin<<<NCLS, 512, 0, stream>>>(protoSum, cursors, pBf, p2);
    k_logits<<<LGRID, 256, 0, stream>>>(emb, labels, pBf, p2,
                                        lossAcc, accAcc, doneCnt, out);
}

// Round 7
// 293.232 us; speedup vs baseline: 1.1334x; 1.0362x over previous
//
#include <hip/hip_runtime.h>
#include <math.h>

#define NROWS 65536
#define DIM   512
#define NCLS  64
#define CCAP  1280   // per-class bucket capacity (mean 1024, sd ~32 -> 8 sigma)

typedef __attribute__((ext_vector_type(4))) float f32x4;
typedef __attribute__((ext_vector_type(8))) short s16x8;

// ws layout (4-byte words):
//   [0..32768)      protoSum[64][512] f32   (zeroed)
//   [32768..32832)  cursors[64] i32         (zeroed; == counts after scatter)
//   32832 lossAcc   32833 accAcc   32834 doneCnt   (zeroed)
//   [32836..32900)  p2[64] f32
//   [32912..114832) perm[64*1280] i32
//   [114944..131328) pBf bf16[64*512] in MFMA B-fragment order
//   ---- extended region (only if ws_size permits) ----
//   [131328..196864)  e2g[65536] f32 (row squared norms)
//   [196864..16974080) ebf bf16[65536*512] row-major A copy (67 MB)
#define WS_PROTOSUM 0
#define WS_CURSORS  32768
#define WS_LOSS     32832
#define WS_ACC      32833
#define WS_DONE     32834
#define WS_P2       32836
#define WS_PERM     32912
#define WS_PBF      114944           // byte 459776, 16B aligned
#define WS_E2G      131328
#define WS_EBF      196864           // byte 787456, 16B aligned
#define WS_EXT_BYTES 67896320ULL     // (196864 + 16777216) * 4
#define MEMSET_WORDS 32835

static __device__ __forceinline__ unsigned short f2bf(float f) {
    unsigned int u = __float_as_uint(f);
    u += 0x7FFF + ((u >> 16) & 1);   // RNE
    return (unsigned short)(u >> 16);
}
static __device__ __forceinline__ float bf2f(unsigned short h) {
    return __uint_as_float(((unsigned int)h) << 16);
}

// ---------------- scatter rows into fixed-stride class buckets ------------
__global__ __launch_bounds__(256) void k_scatter(const int* __restrict__ labels,
                                                 int* __restrict__ cursors,
                                                 int* __restrict__ perm) {
    __shared__ int lh[NCLS], lb[NCLS];
    int t = threadIdx.x;
    if (t < NCLS) lh[t] = 0;
    __syncthreads();
    int i = blockIdx.x * 256 + t;
    int lab = labels[i];
    int rank = atomicAdd(&lh[lab], 1);
    __syncthreads();
    if (t < NCLS) lb[t] = atomicAdd(&cursors[t], lh[t]);
    __syncthreads();
    int pos = lb[lab] + rank;
    if (pos < CCAP) perm[lab * CCAP + pos] = i;
}

// ---------------- per-class partial sums, float4 register accumulation ----
// grid = 64 classes x 4 dim-chunks x 8 row-splits = 2048 blocks
__global__ __launch_bounds__(256) void k_psum(const float* __restrict__ emb,
                                              const int* __restrict__ cursors,
                                              const int* __restrict__ perm,
                                              float* __restrict__ protoSum) {
    __shared__ int permS[CCAP];
    __shared__ float4 red[256];
    int t   = threadIdx.x;
    int c   = blockIdx.x >> 5;
    int sub = blockIdx.x & 31;
    int dc  = sub & 3;        // dim chunk (128 dims)
    int rs  = sub >> 2;       // row split 0..7
    int tl  = t & 31;
    int g   = t >> 5;         // 0..7

    int cnt = cursors[c];
    int n = (cnt < CCAP) ? cnt : CCAP;
    for (int i = t; i < n; i += 256) permS[i] = perm[c * CCAP + i];
    __syncthreads();

    const float4* eb = (const float4*)emb + dc * 32 + tl;
    float4 acc = make_float4(0.f, 0.f, 0.f, 0.f);
#pragma unroll 4
    for (int i = rs * 8 + g; i < n; i += 64) {
        int r = permS[i];                       // LDS broadcast
        float4 v = eb[(size_t)r * 128];         // 512B contiguous per row-grp
        acc.x += v.x; acc.y += v.y; acc.z += v.z; acc.w += v.w;
    }
    red[t] = acc;
    __syncthreads();
    if (t < 32) {
        float4 s = red[t];
#pragma unroll
        for (int gg = 1; gg < 8; ++gg) {
            float4 v = red[gg * 32 + t];
            s.x += v.x; s.y += v.y; s.z += v.z; s.w += v.w;
        }
        float* dst = &protoSum[(size_t)c * DIM + dc * 128 + t * 4];
        atomicAdd(dst + 0, s.x);
        atomicAdd(dst + 1, s.y);
        atomicAdd(dst + 2, s.z);
        atomicAdd(dst + 3, s.w);
    }
}

// ---- finalize prototypes: mean -> bf16 B in MFMA fragment order, p2 ------
// pBf layout: shorts idx = (((kc*4+quad)*4+nt)*16 + l15)*8 + j
__global__ __launch_bounds__(512) void k_protofin(const float* __restrict__ protoSum,
                                                  const int* __restrict__ cursors,
                                                  unsigned short* __restrict__ pBf,
                                                  float* __restrict__ p2) {
    int c = blockIdx.x, d = threadIdx.x;
    float mean = protoSum[(size_t)c * DIM + d] / (float)cursors[c];
    unsigned short mb = f2bf(mean);
    int kc = d >> 5, quad = (d >> 3) & 3, j = d & 7;
    int nt = c >> 4, l15 = c & 15;
    pBf[(size_t)(((kc * 4 + quad) * 4 + nt) * 16 + l15) * 8 + j] = mb;
    float mf = bf2f(mb);
    float sq = mf * mf;
#pragma unroll
    for (int o = 32; o > 0; o >>= 1) sq += __shfl_down(sq, o, 64);
    __shared__ float red[8];
    if ((d & 63) == 0) red[d >> 6] = sq;
    __syncthreads();
    if (d == 0) {
        float ss = 0.f;
#pragma unroll
        for (int w = 0; w < 8; ++w) ss += red[w];
        p2[c] = ss;
    }
}

// ---------------- k_prep: pure streaming emb -> bf16 copy + e2 -----------
// RMSNorm-shaped (G13): grid-stride, one row per wave-iteration, 2 KB
// coalesced read + 1 KB coalesced write + 64-lane butterfly reduce. No MFMA,
// no mixed-latency loads -> the pattern the compiler pipelines deep.
__global__ __launch_bounds__(256) void k_prep(const float* __restrict__ emb,
                                              unsigned short* __restrict__ ebf,
                                              float* __restrict__ e2g) {
    int t = threadIdx.x, lane = t & 63, wv = t >> 6;
    int wid = blockIdx.x * 4 + wv;         // 2048 blocks * 4 waves = 8192
    for (int row = wid; row < NROWS; row += 8192) {
        const float4* rp = (const float4*)(emb + (size_t)row * DIM) + lane * 2;
        float4 v0 = rp[0];
        float4 v1 = rp[1];
        s16x8 h;
        h[0] = f2bf(v0.x); h[1] = f2bf(v0.y); h[2] = f2bf(v0.z); h[3] = f2bf(v0.w);
        h[4] = f2bf(v1.x); h[5] = f2bf(v1.y); h[6] = f2bf(v1.z); h[7] = f2bf(v1.w);
        *(s16x8*)(ebf + (size_t)row * DIM + lane * 8) = h;
        float sq = v0.x * v0.x + v0.y * v0.y + v0.z * v0.z + v0.w * v0.w
                 + v1.x * v1.x + v1.y * v1.y + v1.z * v1.z + v1.w * v1.w;
#pragma unroll
        for (int o = 1; o < 64; o <<= 1) sq += __shfl_xor(sq, o, 64);
        if (lane == 0) e2g[row] = sq;
    }
}

#define LROWS 64
#define LGRID (NROWS / LROWS)

// ---------------- k_logits2: MFMA over L3-hot bf16 A + precomputed e2 -----
// A is ONE 16B fragment load per kc (row-major ebf, fresh in L2/L3), B is
// L2-hot. No f2bf, no e2 chain -> short loop, all latencies cache-scale.
__global__ __launch_bounds__(256, 4) void k_logits2(const unsigned short* __restrict__ ebf,
                                                 const float* __restrict__ e2g,
                                                 const int* __restrict__ labels,
                                                 const unsigned short* __restrict__ pBf,
                                                 const float* __restrict__ p2,
                                                 float* __restrict__ lossAcc,
                                                 float* __restrict__ accAcc,
                                                 unsigned int* __restrict__ doneCnt,
                                                 float* __restrict__ out) {
    __shared__ float rb[8];
    int t    = threadIdx.x;
    int lane = t & 63;
    int wv   = t >> 6;
    int quad = lane >> 4;
    int l15  = lane & 15;
    int rbase = blockIdx.x * LROWS;
    int row   = wv * 16 + l15;

    f32x4 acc[4];
#pragma unroll
    for (int nt = 0; nt < 4; ++nt) acc[nt] = (f32x4){0.f, 0.f, 0.f, 0.f};

    // s16x8 units: frag (kc,quad) at shorts offset kc*32+quad*8 -> idx kc*4+quad
    const s16x8* ap = (const s16x8*)(ebf + (size_t)(rbase + row) * DIM) + quad;
    const s16x8* bp = (const s16x8*)pBf + quad * 64 + l15;

#pragma unroll 4
    for (int kc = 0; kc < 16; ++kc) {
        s16x8 a = ap[kc * 4];
#pragma unroll
        for (int nt = 0; nt < 4; ++nt) {
            s16x8 b = bp[(size_t)kc * 256 + nt * 16];
            acc[nt] = __builtin_amdgcn_mfma_f32_16x16x32_bf16(a, b, acc[nt], 0, 0, 0);
        }
    }

    // epilogue: C/D layout col = nt*16 + l15, row = quad*4 + reg
    float nlls = 0.f, corr = 0.f;
#pragma unroll
    for (int reg = 0; reg < 4; ++reg) {
        int rloc = wv * 16 + quad * 4 + reg;
        float e2v = e2g[rbase + rloc];
        float lg[4];
#pragma unroll
        for (int nt = 0; nt < 4; ++nt) {
            float d2 = e2v + p2[nt * 16 + l15] - 2.f * acc[nt][reg];
            d2 = fmaxf(d2, 1e-12f);
            lg[nt] = -sqrtf(d2);
        }
        float mv = lg[0]; int mc = l15;
#pragma unroll
        for (int nt = 1; nt < 4; ++nt) {
            int cix = nt * 16 + l15;
            if (lg[nt] > mv) { mv = lg[nt]; mc = cix; }
        }
#pragma unroll
        for (int o = 1; o < 16; o <<= 1) {
            float mo = __shfl_xor(mv, o, 64);
            int   co = __shfl_xor(mc, o, 64);
            if (mo > mv || (mo == mv && co < mc)) { mv = mo; mc = co; }
        }
        int lab = labels[rbase + rloc];
        float se = 0.f, ll = 0.f;
#pragma unroll
        for (int nt = 0; nt < 4; ++nt) se += __expf(lg[nt] - mv);
        if ((lab & 15) == l15) ll = lg[lab >> 4];
#pragma unroll
        for (int o = 1; o < 16; o <<= 1) {
            se += __shfl_xor(se, o, 64);
            ll += __shfl_xor(ll, o, 64);
        }
        if (l15 == 0) {
            nlls += __logf(se) + mv - ll;
            corr += (mc == lab) ? 1.f : 0.f;
        }
    }
#pragma unroll
    for (int o = 1; o < 64; o <<= 1) {
        nlls += __shfl_xor(nlls, o, 64);
        corr += __shfl_xor(corr, o, 64);
    }
    if (lane == 0) { rb[wv] = nlls; rb[4 + wv] = corr; }
    __syncthreads();
    if (t == 0) {
        atomicAdd(lossAcc, rb[0] + rb[1] + rb[2] + rb[3]);
        atomicAdd(accAcc, rb[4] + rb[5] + rb[6] + rb[7]);
        __threadfence();
        unsigned int tk = atomicAdd(doneCnt, 1u);
        if (tk == LGRID - 1) {   // last block: all atomics visible
            float ls  = atomicAdd(lossAcc, 0.f);   // device-scope read
            float as_ = atomicAdd(accAcc, 0.f);
            out[0] = ls * (1.f / NROWS);
            out[1] = as_ * (1.f / NROWS);
        }
    }
}

// ---------------- fallback k_logits (exact R1 structure, proven 79 us) ----
__global__ __launch_bounds__(256) void k_logits(const float* __restrict__ emb,
                                                const int* __restrict__ labels,
                                                const unsigned short* __restrict__ pBf,
                                                const float* __restrict__ p2,
                                                float* __restrict__ lossAcc,
                                                float* __restrict__ accAcc,
                                                unsigned int* __restrict__ doneCnt,
                                                float* __restrict__ out) {
    __shared__ float e2s[LROWS];
    __shared__ float rb[8];

    int t    = threadIdx.x;
    int lane = t & 63;
    int wv   = t >> 6;
    int quad = lane >> 4;
    int l15  = lane & 15;
    int rbase = blockIdx.x * LROWS;
    int row   = wv * 16 + l15;

    f32x4 acc[4];
#pragma unroll
    for (int nt = 0; nt < 4; ++nt) acc[nt] = (f32x4){0.f, 0.f, 0.f, 0.f};
    float e2a = 0.f;

    const float4* rp = (const float4*)(emb + (size_t)(rbase + row) * DIM) + quad * 2;
    const s16x8*  bp = (const s16x8*)pBf + quad * 64 + l15;

#pragma unroll 4
    for (int kc = 0; kc < 16; ++kc) {
        float4 g0 = rp[kc * 8];
        float4 g1 = rp[kc * 8 + 1];
        e2a += g0.x * g0.x + g0.y * g0.y + g0.z * g0.z + g0.w * g0.w
             + g1.x * g1.x + g1.y * g1.y + g1.z * g1.z + g1.w * g1.w;
        s16x8 a;
        a[0] = f2bf(g0.x); a[1] = f2bf(g0.y); a[2] = f2bf(g0.z); a[3] = f2bf(g0.w);
        a[4] = f2bf(g1.x); a[5] = f2bf(g1.y); a[6] = f2bf(g1.z); a[7] = f2bf(g1.w);
#pragma unroll
        for (int nt = 0; nt < 4; ++nt) {
            s16x8 b = bp[(size_t)kc * 256 + nt * 16];
            acc[nt] = __builtin_amdgcn_mfma_f32_16x16x32_bf16(a, b, acc[nt], 0, 0, 0);
        }
    }

    e2a += __shfl_xor(e2a, 16, 64);
    e2a += __shfl_xor(e2a, 32, 64);
    if (quad == 0) e2s[row] = e2a;
    __syncthreads();

    float nlls = 0.f, corr = 0.f;
#pragma unroll
    for (int reg = 0; reg < 4; ++reg) {
        int rloc = wv * 16 + quad * 4 + reg;
        float e2v = e2s[rloc];
        float lg[4];
#pragma unroll
        for (int nt = 0; nt < 4; ++nt) {
            float d2 = e2v + p2[nt * 16 + l15] - 2.f * acc[nt][reg];
            d2 = fmaxf(d2, 1e-12f);
            lg[nt] = -sqrtf(d2);
        }
        float mv = lg[0]; int mc = l15;
#pragma unroll
        for (int nt = 1; nt < 4; ++nt) {
            int cix = nt * 16 + l15;
            if (lg[nt] > mv) { mv = lg[nt]; mc = cix; }
        }
#pragma unroll
        for (int o = 1; o < 16; o <<= 1) {
            float mo = __shfl_xor(mv, o, 64);
            int   co = __shfl_xor(mc, o, 64);
            if (mo > mv || (mo == mv && co < mc)) { mv = mo; mc = co; }
        }
        int lab = labels[rbase + rloc];
        float se = 0.f, ll = 0.f;
#pragma unroll
        for (int nt = 0; nt < 4; ++nt) se += __expf(lg[nt] - mv);
        if ((lab & 15) == l15) ll = lg[lab >> 4];
#pragma unroll
        for (int o = 1; o < 16; o <<= 1) {
            se += __shfl_xor(se, o, 64);
            ll += __shfl_xor(ll, o, 64);
        }
        if (l15 == 0) {
            nlls += __logf(se) + mv - ll;
            corr += (mc == lab) ? 1.f : 0.f;
        }
    }
#pragma unroll
    for (int o = 1; o < 64; o <<= 1) {
        nlls += __shfl_xor(nlls, o, 64);
        corr += __shfl_xor(corr, o, 64);
    }
    if (lane == 0) { rb[wv] = nlls; rb[4 + wv] = corr; }
    __syncthreads();
    if (t == 0) {
        atomicAdd(lossAcc, rb[0] + rb[1] + rb[2] + rb[3]);
        atomicAdd(accAcc, rb[4] + rb[5] + rb[6] + rb[7]);
        __threadfence();
        unsigned int tk = atomicAdd(doneCnt, 1u);
        if (tk == LGRID - 1) {
            float ls  = atomicAdd(lossAcc, 0.f);
            float as_ = atomicAdd(accAcc, 0.f);
            out[0] = ls * (1.f / NROWS);
            out[1] = as_ * (1.f / NROWS);
        }
    }
}

extern "C" void kernel_launch(void* const* d_in, const int* in_sizes, int n_in,
                              void* d_out, int out_size, void* d_ws, size_t ws_size,
                              hipStream_t stream) {
    const float* emb    = (const float*)d_in[0];
    const int*   labels = (const int*)d_in[1];
    float* out = (float*)d_out;

    float* wsf = (float*)d_ws;
    int*   wsi = (int*)d_ws;
    float*          protoSum = wsf + WS_PROTOSUM;
    int*            cursors  = wsi + WS_CURSORS;
    float*          lossAcc  = wsf + WS_LOSS;
    float*          accAcc   = wsf + WS_ACC;
    unsigned int*   doneCnt  = (unsigned int*)(wsi + WS_DONE);
    float*          p2       = wsf + WS_P2;
    int*            perm     = wsi + WS_PERM;
    unsigned short* pBf      = (unsigned short*)(wsf + WS_PBF);
    float*          e2g      = wsf + WS_E2G;
    unsigned short* ebf      = (unsigned short*)(wsf + WS_EBF);

    hipMemsetAsync(d_ws, 0, MEMSET_WORDS * sizeof(int), stream);

    k_scatter<<<NROWS / 256, 256, 0, stream>>>(labels, cursors, perm);
    if (ws_size >= WS_EXT_BYTES) {
        k_prep<<<2048, 256, 0, stream>>>(emb, ebf, e2g);
        k_psum<<<NCLS * 32, 256, 0, stream>>>(emb, cursors, perm, protoSum);
        k_protofin<<<NCLS, 512, 0, stream>>>(protoSum, cursors, pBf, p2);
        k_logits2<<<LGRID, 256, 0, stream>>>(ebf, e2g, labels, pBf, p2,
                                             lossAcc, accAcc, doneCnt, out);
    } else {
        k_psum<<<NCLS * 32, 256, 0, stream>>>(emb, cursors, perm, protoSum);
        k_protofin<<<NCLS, 512, 0, stream>>>(protoSum, cursors, pBf, p2);
        k_logits<<<LGRID, 256, 0, stream>>>(emb, labels, pBf, p2,
                                            lossAcc, accAcc, doneCnt, out);
    }
}

// Round 8
// 279.532 us; speedup vs baseline: 1.1889x; 1.0490x over previous
//
#include <hip/hip_runtime.h>
#include <math.h>

#define NROWS 65536
#define DIM   512
#define NCLS  64
#define CCAP  1280   // per-class bucket capacity (mean 1024, sd ~32 -> 8 sigma)

typedef __attribute__((ext_vector_type(4))) float f32x4;
typedef __attribute__((ext_vector_type(8))) short s16x8;

// ws layout (4-byte words):
//   [0..32768)      protoSum[64][512] f32   (zeroed)
//   [32768..32832)  cursors[64] i32         (zeroed; == counts after scatter)
//   32832 lossAcc   32833 accAcc   32834 doneCnt   (zeroed)
//   [32836..32900)  p2[64] f32
//   [32912..114832) perm[64*1280] i32
//   [114944..131328) pBf bf16[64*512] in MFMA B-fragment order
//   ---- extended region (only if ws_size permits) ----
//   [131328..393472)  e2p[4][65536] f32 (per-128-dim-chunk row sq-norm partials)
//   [393472..17170688) ebf bf16[65536*512] row-major A copy (67 MB)
#define WS_PROTOSUM 0
#define WS_CURSORS  32768
#define WS_LOSS     32832
#define WS_ACC      32833
#define WS_DONE     32834
#define WS_P2       32836
#define WS_PERM     32912
#define WS_PBF      114944           // byte 459776, 16B aligned
#define WS_E2P      131328
#define WS_EBF      393472           // byte 1573888, 16B aligned
#define WS_EXT_BYTES 68682752ULL     // (393472 + 16777216) * 4
#define MEMSET_WORDS 32835

static __device__ __forceinline__ unsigned short f2bf(float f) {
    unsigned int u = __float_as_uint(f);
    u += 0x7FFF + ((u >> 16) & 1);   // RNE
    return (unsigned short)(u >> 16);
}
static __device__ __forceinline__ float bf2f(unsigned short h) {
    return __uint_as_float(((unsigned int)h) << 16);
}

// ---------------- scatter rows into fixed-stride class buckets ------------
__global__ __launch_bounds__(256) void k_scatter(const int* __restrict__ labels,
                                                 int* __restrict__ cursors,
                                                 int* __restrict__ perm) {
    __shared__ int lh[NCLS], lb[NCLS];
    int t = threadIdx.x;
    if (t < NCLS) lh[t] = 0;
    __syncthreads();
    int i = blockIdx.x * 256 + t;
    int lab = labels[i];
    int rank = atomicAdd(&lh[lab], 1);
    __syncthreads();
    if (t < NCLS) lb[t] = atomicAdd(&cursors[t], lh[t]);
    __syncthreads();
    int pos = lb[lab] + rank;
    if (pos < CCAP) perm[lab * CCAP + pos] = i;
}

// ------- FUSED psum + prep: class sums AND ebf/e2 in ONE emb pass ---------
// grid = 64 classes x 4 dim-chunks x 8 row-splits = 2048 blocks.
// Per row-chunk (512B, held in registers): f32 class-sum accumulation
// (unchanged math), bf16 convert + 8B/lane store (256B contiguous per
// row-group), and a 5-step half-wave shuffle e2 partial -> e2p[dc][row]
// (non-atomic: each (dc,row) written exactly once via perm).
__global__ __launch_bounds__(256) void k_psumprep(const float* __restrict__ emb,
                                                  const int* __restrict__ cursors,
                                                  const int* __restrict__ perm,
                                                  float* __restrict__ protoSum,
                                                  unsigned short* __restrict__ ebf,
                                                  float* __restrict__ e2p) {
    __shared__ int permS[CCAP];
    __shared__ float4 red[256];
    int t   = threadIdx.x;
    int c   = blockIdx.x >> 5;
    int sub = blockIdx.x & 31;
    int dc  = sub & 3;        // dim chunk (128 dims)
    int rs  = sub >> 2;       // row split 0..7
    int tl  = t & 31;
    int g   = t >> 5;         // 0..7

    int cnt = cursors[c];
    int n = (cnt < CCAP) ? cnt : CCAP;
    for (int i = t; i < n; i += 256) permS[i] = perm[c * CCAP + i];
    __syncthreads();

    const float4* eb = (const float4*)emb + dc * 32 + tl;
    float* e2o = e2p + (size_t)dc * NROWS;
    float4 acc = make_float4(0.f, 0.f, 0.f, 0.f);
#pragma unroll 2
    for (int i = rs * 8 + g; i < n; i += 64) {
        int r = permS[i];                       // LDS broadcast
        float4 v = eb[(size_t)r * 128];         // 512B contiguous per row-grp
        acc.x += v.x; acc.y += v.y; acc.z += v.z; acc.w += v.w;
        ushort4 h;
        h.x = f2bf(v.x); h.y = f2bf(v.y); h.z = f2bf(v.z); h.w = f2bf(v.w);
        *(ushort4*)(ebf + (size_t)r * DIM + dc * 128 + tl * 4) = h;
        float sq = v.x * v.x + v.y * v.y + v.z * v.z + v.w * v.w;
#pragma unroll
        for (int o = 1; o < 32; o <<= 1) sq += __shfl_xor(sq, o, 64);
        if (tl == 0) e2o[r] = sq;
    }
    red[t] = acc;
    __syncthreads();
    if (t < 32) {
        float4 s = red[t];
#pragma unroll
        for (int gg = 1; gg < 8; ++gg) {
            float4 v = red[gg * 32 + t];
            s.x += v.x; s.y += v.y; s.z += v.z; s.w += v.w;
        }
        float* dst = &protoSum[(size_t)c * DIM + dc * 128 + t * 4];
        atomicAdd(dst + 0, s.x);
        atomicAdd(dst + 1, s.y);
        atomicAdd(dst + 2, s.z);
        atomicAdd(dst + 3, s.w);
    }
}

// ---------------- plain psum (fallback path only) -------------------------
__global__ __launch_bounds__(256) void k_psum(const float* __restrict__ emb,
                                              const int* __restrict__ cursors,
                                              const int* __restrict__ perm,
                                              float* __restrict__ protoSum) {
    __shared__ int permS[CCAP];
    __shared__ float4 red[256];
    int t   = threadIdx.x;
    int c   = blockIdx.x >> 5;
    int sub = blockIdx.x & 31;
    int dc  = sub & 3;
    int rs  = sub >> 2;
    int tl  = t & 31;
    int g   = t >> 5;

    int cnt = cursors[c];
    int n = (cnt < CCAP) ? cnt : CCAP;
    for (int i = t; i < n; i += 256) permS[i] = perm[c * CCAP + i];
    __syncthreads();

    const float4* eb = (const float4*)emb + dc * 32 + tl;
    float4 acc = make_float4(0.f, 0.f, 0.f, 0.f);
#pragma unroll 4
    for (int i = rs * 8 + g; i < n; i += 64) {
        int r = permS[i];
        float4 v = eb[(size_t)r * 128];
        acc.x += v.x; acc.y += v.y; acc.z += v.z; acc.w += v.w;
    }
    red[t] = acc;
    __syncthreads();
    if (t < 32) {
        float4 s = red[t];
#pragma unroll
        for (int gg = 1; gg < 8; ++gg) {
            float4 v = red[gg * 32 + t];
            s.x += v.x; s.y += v.y; s.z += v.z; s.w += v.w;
        }
        float* dst = &protoSum[(size_t)c * DIM + dc * 128 + t * 4];
        atomicAdd(dst + 0, s.x);
        atomicAdd(dst + 1, s.y);
        atomicAdd(dst + 2, s.z);
        atomicAdd(dst + 3, s.w);
    }
}

// ---- finalize prototypes: mean -> bf16 B in MFMA fragment order, p2 ------
// pBf layout: shorts idx = (((kc*4+quad)*4+nt)*16 + l15)*8 + j
__global__ __launch_bounds__(512) void k_protofin(const float* __restrict__ protoSum,
                                                  const int* __restrict__ cursors,
                                                  unsigned short* __restrict__ pBf,
                                                  float* __restrict__ p2) {
    int c = blockIdx.x, d = threadIdx.x;
    float mean = protoSum[(size_t)c * DIM + d] / (float)cursors[c];
    unsigned short mb = f2bf(mean);
    int kc = d >> 5, quad = (d >> 3) & 3, j = d & 7;
    int nt = c >> 4, l15 = c & 15;
    pBf[(size_t)(((kc * 4 + quad) * 4 + nt) * 16 + l15) * 8 + j] = mb;
    float mf = bf2f(mb);
    float sq = mf * mf;
#pragma unroll
    for (int o = 32; o > 0; o >>= 1) sq += __shfl_down(sq, o, 64);
    __shared__ float red[8];
    if ((d & 63) == 0) red[d >> 6] = sq;
    __syncthreads();
    if (d == 0) {
        float ss = 0.f;
#pragma unroll
        for (int w = 0; w < 8; ++w) ss += red[w];
        p2[c] = ss;
    }
}

#define LROWS 64
#define LGRID (NROWS / LROWS)

// ---------------- k_logits2: MFMA over L3-hot bf16 A + precomputed e2 -----
__global__ __launch_bounds__(256, 4) void k_logits2(const unsigned short* __restrict__ ebf,
                                                 const float* __restrict__ e2p,
                                                 const int* __restrict__ labels,
                                                 const unsigned short* __restrict__ pBf,
                                                 const float* __restrict__ p2,
                                                 float* __restrict__ lossAcc,
                                                 float* __restrict__ accAcc,
                                                 unsigned int* __restrict__ doneCnt,
                                                 float* __restrict__ out) {
    __shared__ float rb[8];
    int t    = threadIdx.x;
    int lane = t & 63;
    int wv   = t >> 6;
    int quad = lane >> 4;
    int l15  = lane & 15;
    int rbase = blockIdx.x * LROWS;
    int row   = wv * 16 + l15;

    f32x4 acc[4];
#pragma unroll
    for (int nt = 0; nt < 4; ++nt) acc[nt] = (f32x4){0.f, 0.f, 0.f, 0.f};

    // s16x8 units: frag (kc,quad) at shorts offset kc*32+quad*8 -> idx kc*4+quad
    const s16x8* ap = (const s16x8*)(ebf + (size_t)(rbase + row) * DIM) + quad;
    const s16x8* bp = (const s16x8*)pBf + quad * 64 + l15;

#pragma unroll 4
    for (int kc = 0; kc < 16; ++kc) {
        s16x8 a = ap[kc * 4];
#pragma unroll
        for (int nt = 0; nt < 4; ++nt) {
            s16x8 b = bp[(size_t)kc * 256 + nt * 16];
            acc[nt] = __builtin_amdgcn_mfma_f32_16x16x32_bf16(a, b, acc[nt], 0, 0, 0);
        }
    }

    // epilogue: C/D layout col = nt*16 + l15, row = quad*4 + reg
    float nlls = 0.f, corr = 0.f;
#pragma unroll
    for (int reg = 0; reg < 4; ++reg) {
        int rloc = wv * 16 + quad * 4 + reg;
        int grow = rbase + rloc;
        float e2v = e2p[grow] + e2p[NROWS + grow]
                  + e2p[2 * NROWS + grow] + e2p[3 * NROWS + grow];
        float lg[4];
#pragma unroll
        for (int nt = 0; nt < 4; ++nt) {
            float d2 = e2v + p2[nt * 16 + l15] - 2.f * acc[nt][reg];
            d2 = fmaxf(d2, 1e-12f);
            lg[nt] = -sqrtf(d2);
        }
        float mv = lg[0]; int mc = l15;
#pragma unroll
        for (int nt = 1; nt < 4; ++nt) {
            int cix = nt * 16 + l15;
            if (lg[nt] > mv) { mv = lg[nt]; mc = cix; }
        }
#pragma unroll
        for (int o = 1; o < 16; o <<= 1) {
            float mo = __shfl_xor(mv, o, 64);
            int   co = __shfl_xor(mc, o, 64);
            if (mo > mv || (mo == mv && co < mc)) { mv = mo; mc = co; }
        }
        int lab = labels[grow];
        float se = 0.f, ll = 0.f;
#pragma unroll
        for (int nt = 0; nt < 4; ++nt) se += __expf(lg[nt] - mv);
        if ((lab & 15) == l15) ll = lg[lab >> 4];
#pragma unroll
        for (int o = 1; o < 16; o <<= 1) {
            se += __shfl_xor(se, o, 64);
            ll += __shfl_xor(ll, o, 64);
        }
        if (l15 == 0) {
            nlls += __logf(se) + mv - ll;
            corr += (mc == lab) ? 1.f : 0.f;
        }
    }
#pragma unroll
    for (int o = 1; o < 64; o <<= 1) {
        nlls += __shfl_xor(nlls, o, 64);
        corr += __shfl_xor(corr, o, 64);
    }
    if (lane == 0) { rb[wv] = nlls; rb[4 + wv] = corr; }
    __syncthreads();
    if (t == 0) {
        atomicAdd(lossAcc, rb[0] + rb[1] + rb[2] + rb[3]);
        atomicAdd(accAcc, rb[4] + rb[5] + rb[6] + rb[7]);
        __threadfence();
        unsigned int tk = atomicAdd(doneCnt, 1u);
        if (tk == LGRID - 1) {   // last block: all atomics visible
            float ls  = atomicAdd(lossAcc, 0.f);   // device-scope read
            float as_ = atomicAdd(accAcc, 0.f);
            out[0] = ls * (1.f / NROWS);
            out[1] = as_ * (1.f / NROWS);
        }
    }
}

// ---------------- fallback k_logits (exact R1 structure, proven 79 us) ----
__global__ __launch_bounds__(256) void k_logits(const float* __restrict__ emb,
                                                const int* __restrict__ labels,
                                                const unsigned short* __restrict__ pBf,
                                                const float* __restrict__ p2,
                                                float* __restrict__ lossAcc,
                                                float* __restrict__ accAcc,
                                                unsigned int* __restrict__ doneCnt,
                                                float* __restrict__ out) {
    __shared__ float e2s[LROWS];
    __shared__ float rb[8];

    int t    = threadIdx.x;
    int lane = t & 63;
    int wv   = t >> 6;
    int quad = lane >> 4;
    int l15  = lane & 15;
    int rbase = blockIdx.x * LROWS;
    int row   = wv * 16 + l15;

    f32x4 acc[4];
#pragma unroll
    for (int nt = 0; nt < 4; ++nt) acc[nt] = (f32x4){0.f, 0.f, 0.f, 0.f};
    float e2a = 0.f;

    const float4* rp = (const float4*)(emb + (size_t)(rbase + row) * DIM) + quad * 2;
    const s16x8*  bp = (const s16x8*)pBf + quad * 64 + l15;

#pragma unroll 4
    for (int kc = 0; kc < 16; ++kc) {
        float4 g0 = rp[kc * 8];
        float4 g1 = rp[kc * 8 + 1];
        e2a += g0.x * g0.x + g0.y * g0.y + g0.z * g0.z + g0.w * g0.w
             + g1.x * g1.x + g1.y * g1.y + g1.z * g1.z + g1.w * g1.w;
        s16x8 a;
        a[0] = f2bf(g0.x); a[1] = f2bf(g0.y); a[2] = f2bf(g0.z); a[3] = f2bf(g0.w);
        a[4] = f2bf(g1.x); a[5] = f2bf(g1.y); a[6] = f2bf(g1.z); a[7] = f2bf(g1.w);
#pragma unroll
        for (int nt = 0; nt < 4; ++nt) {
            s16x8 b = bp[(size_t)kc * 256 + nt * 16];
            acc[nt] = __builtin_amdgcn_mfma_f32_16x16x32_bf16(a, b, acc[nt], 0, 0, 0);
        }
    }

    e2a += __shfl_xor(e2a, 16, 64);
    e2a += __shfl_xor(e2a, 32, 64);
    if (quad == 0) e2s[row] = e2a;
    __syncthreads();

    float nlls = 0.f, corr = 0.f;
#pragma unroll
    for (int reg = 0; reg < 4; ++reg) {
        int rloc = wv * 16 + quad * 4 + reg;
        float e2v = e2s[rloc];
        float lg[4];
#pragma unroll
        for (int nt = 0; nt < 4; ++nt) {
            float d2 = e2v + p2[nt * 16 + l15] - 2.f * acc[nt][reg];
            d2 = fmaxf(d2, 1e-12f);
            lg[nt] = -sqrtf(d2);
        }
        float mv = lg[0]; int mc = l15;
#pragma unroll
        for (int nt = 1; nt < 4; ++nt) {
            int cix = nt * 16 + l15;
            if (lg[nt] > mv) { mv = lg[nt]; mc = cix; }
        }
#pragma unroll
        for (int o = 1; o < 16; o <<= 1) {
            float mo = __shfl_xor(mv, o, 64);
            int   co = __shfl_xor(mc, o, 64);
            if (mo > mv || (mo == mv && co < mc)) { mv = mo; mc = co; }
        }
        int lab = labels[rbase + rloc];
        float se = 0.f, ll = 0.f;
#pragma unroll
        for (int nt = 0; nt < 4; ++nt) se += __expf(lg[nt] - mv);
        if ((lab & 15) == l15) ll = lg[lab >> 4];
#pragma unroll
        for (int o = 1; o < 16; o <<= 1) {
            se += __shfl_xor(se, o, 64);
            ll += __shfl_xor(ll, o, 64);
        }
        if (l15 == 0) {
            nlls += __logf(se) + mv - ll;
            corr += (mc == lab) ? 1.f : 0.f;
        }
    }
#pragma unroll
    for (int o = 1; o < 64; o <<= 1) {
        nlls += __shfl_xor(nlls, o, 64);
        corr += __shfl_xor(corr, o, 64);
    }
    if (lane == 0) { rb[wv] = nlls; rb[4 + wv] = corr; }
    __syncthreads();
    if (t == 0) {
        atomicAdd(lossAcc, rb[0] + rb[1] + rb[2] + rb[3]);
        atomicAdd(accAcc, rb[4] + rb[5] + rb[6] + rb[7]);
        __threadfence();
        unsigned int tk = atomicAdd(doneCnt, 1u);
        if (tk == LGRID - 1) {
            float ls  = atomicAdd(lossAcc, 0.f);
            float as_ = atomicAdd(accAcc, 0.f);
            out[0] = ls * (1.f / NROWS);
            out[1] = as_ * (1.f / NROWS);
        }
    }
}

extern "C" void kernel_launch(void* const* d_in, const int* in_sizes, int n_in,
                              void* d_out, int out_size, void* d_ws, size_t ws_size,
                              hipStream_t stream) {
    const float* emb    = (const float*)d_in[0];
    const int*   labels = (const int*)d_in[1];
    float* out = (float*)d_out;

    float* wsf = (float*)d_ws;
    int*   wsi = (int*)d_ws;
    float*          protoSum = wsf + WS_PROTOSUM;
    int*            cursors  = wsi + WS_CURSORS;
    float*          lossAcc  = wsf + WS_LOSS;
    float*          accAcc   = wsf + WS_ACC;
    unsigned int*   doneCnt  = (unsigned int*)(wsi + WS_DONE);
    float*          p2       = wsf + WS_P2;
    int*            perm     = wsi + WS_PERM;
    unsigned short* pBf      = (unsigned short*)(wsf + WS_PBF);
    float*          e2p      = wsf + WS_E2P;
    unsigned short* ebf      = (unsigned short*)(wsf + WS_EBF);

    hipMemsetAsync(d_ws, 0, MEMSET_WORDS * sizeof(int), stream);

    k_scatter<<<NROWS / 256, 256, 0, stream>>>(labels, cursors, perm);
    if (ws_size >= WS_EXT_BYTES) {
        k_psumprep<<<NCLS * 32, 256, 0, stream>>>(emb, cursors, perm, protoSum,
                                                  ebf, e2p);
        k_protofin<<<NCLS, 512, 0, stream>>>(protoSum, cursors, pBf, p2);
        k_logits2<<<LGRID, 256, 0, stream>>>(ebf, e2p, labels, pBf, p2,
                                             lossAcc, accAcc, doneCnt, out);
    } else {
        k_psum<<<NCLS * 32, 256, 0, stream>>>(emb, cursors, perm, protoSum);
        k_protofin<<<NCLS, 512, 0, stream>>>(protoSum, cursors, pBf, p2);
        k_logits<<<LGRID, 256, 0, stream>>>(emb, labels, pBf, p2,
                                            lossAcc, accAcc, doneCnt, out);
    }
}